// Round 15
// baseline (140.199 us; speedup 1.0000x reference)
//
#include <hip/hip_runtime.h>
#include <hip/hip_bf16.h>

typedef __attribute__((ext_vector_type(8))) short bf16x8;
typedef __attribute__((ext_vector_type(4))) float f32x4;
typedef __attribute__((ext_vector_type(16))) float f32x16;

#define MFMA16(a,b,c) __builtin_amdgcn_mfma_f32_16x16x32_bf16(a,b,c,0,0,0)
#define MFMA32(a,b,c) __builtin_amdgcn_mfma_f32_32x32x16_bf16(a,b,c,0,0,0)

#if __has_builtin(__builtin_amdgcn_exp2f)
#define EXP2(x) __builtin_amdgcn_exp2f(x)
#else
#define EXP2(x) exp2f(x)
#endif

#define B_   2
#define T_   2048
#define D_   1024
#define H_   16
#define DH_  64
#define BH_  (B_*H_)
#define M_   (B_*T_)   // 4096 token rows

// NOTE (rounds 13/14 lesson): an xswap32 helper built from
// v_permlane32_swap with BOTH operands initialized to the same value NaN'd
// twice — likely register-coalescing to v_permlane32_swap v, v (same-operand
// behavior unverified). permlane32_swap is used ONLY with distinct-valued
// operands (the verified PV pattern). Cross-half reduce stays __shfl_xor.

// ---------------- fp32 -> bf16 converts -----------------------------------
__global__ void cvt_f32_bf16(const float* __restrict__ in,
                             __hip_bfloat16* __restrict__ out, int n4) {
    int i = blockIdx.x * blockDim.x + threadIdx.x;
    if (i >= n4) return;
    float4 v = ((const float4*)in)[i];
    union { ushort4 u; __hip_bfloat16 h[4]; } r;
    r.h[0] = __float2bfloat16(v.x);
    r.h[1] = __float2bfloat16(v.y);
    r.h[2] = __float2bfloat16(v.z);
    r.h[3] = __float2bfloat16(v.w);
    ((ushort4*)out)[i] = r.u;
}

__global__ void cvt4_f32_bf16(const float* __restrict__ w0, const float* __restrict__ w1,
                              const float* __restrict__ w2, const float* __restrict__ w3,
                              __hip_bfloat16* __restrict__ o0, __hip_bfloat16* __restrict__ o1,
                              __hip_bfloat16* __restrict__ o2, __hip_bfloat16* __restrict__ o3,
                              int n4) {
    int i = blockIdx.x * blockDim.x + threadIdx.x;
    if (i >= n4) return;
    const float* in = (blockIdx.y == 0) ? w0 : (blockIdx.y == 1) ? w1 : (blockIdx.y == 2) ? w2 : w3;
    __hip_bfloat16* out = (blockIdx.y == 0) ? o0 : (blockIdx.y == 1) ? o1 : (blockIdx.y == 2) ? o2 : o3;
    float4 v = ((const float4*)in)[i];
    union { ushort4 u; __hip_bfloat16 h[4]; } r;
    r.h[0] = __float2bfloat16(v.x);
    r.h[1] = __float2bfloat16(v.y);
    r.h[2] = __float2bfloat16(v.z);
    r.h[3] = __float2bfloat16(v.w);
    ((ushort4*)out)[i] = r.u;
}

// ---------------- fused QKV GEMM (128x128 m97 structure + T2 swizzle) -----
// 768 blocks (3/CU); MFMA:ds_read = 2.0; staging traffic halved vs 64x128.
// Swizzle: pre-swizzled global source col + same-XOR read (rule 21).
__global__ __launch_bounds__(256)
void gemm_qkv(const __hip_bfloat16* __restrict__ A,
              const __hip_bfloat16* __restrict__ Wq_, const __hip_bfloat16* __restrict__ Wk_,
              const __hip_bfloat16* __restrict__ Wv_,
              const float* __restrict__ bq_, const float* __restrict__ bk_,
              const float* __restrict__ bv_,
              __hip_bfloat16* __restrict__ Qh, __hip_bfloat16* __restrict__ Kh,
              __hip_bfloat16* __restrict__ Vth)
{
    __shared__ __hip_bfloat16 As[128][64];
    __shared__ __hip_bfloat16 Bs[128][64];
    const int tid = threadIdx.x;
    const int lane = tid & 63, w = tid >> 6;
    const int lr = lane & 15, lg = lane >> 4;
    const int wr = w >> 1, wc = w & 1;
    const int which = blockIdx.x >> 3;
    const int n0 = (blockIdx.x & 7) * 128;
    const int m0 = blockIdx.y * 128;

    const __hip_bfloat16* Bw = (which == 0) ? Wq_ : (which == 1) ? Wk_ : Wv_;
    const float* bias         = (which == 0) ? bq_ : (which == 1) ? bk_ : bv_;
    __hip_bfloat16* Cout      = (which == 0) ? Qh  : (which == 1) ? Kh  : Vth;

    f32x4 acc[4][4] = {};

    const int grow = w * 32 + (lane >> 3);                 // row; row&7 = lane>>3
    const int scol = ((lane & 7) ^ (lane >> 3)) * 8;       // pre-swizzled src col
    const int rswz = (lr & 7) * 8;                         // read-side XOR

    for (int k0 = 0; k0 < D_; k0 += 64) {
#pragma unroll
        for (int c = 0; c < 4; ++c) {
            __builtin_amdgcn_global_load_lds(
                (const __attribute__((address_space(1))) void*)
                    &A[(size_t)(m0 + grow + c * 8) * D_ + k0 + scol],
                (__attribute__((address_space(3))) void*)&As[w * 32 + c * 8][0],
                16, 0, 0);
            __builtin_amdgcn_global_load_lds(
                (const __attribute__((address_space(1))) void*)
                    &Bw[(size_t)(n0 + grow + c * 8) * D_ + k0 + scol],
                (__attribute__((address_space(3))) void*)&Bs[w * 32 + c * 8][0],
                16, 0, 0);
        }
        __syncthreads();
#pragma unroll
        for (int ks = 0; ks < 2; ++ks) {
            bf16x8 af[4], bfr[4];
            for (int mi = 0; mi < 4; ++mi)
                af[mi]  = *(const bf16x8*)&As[wr * 64 + mi * 16 + lr][(ks * 32 + lg * 8) ^ rswz];
            for (int ni = 0; ni < 4; ++ni)
                bfr[ni] = *(const bf16x8*)&Bs[wc * 64 + ni * 16 + lr][(ks * 32 + lg * 8) ^ rswz];
            for (int mi = 0; mi < 4; ++mi)
                for (int ni = 0; ni < 4; ++ni)
                    acc[mi][ni] = MFMA16(af[mi], bfr[ni], acc[mi][ni]);
        }
        __syncthreads();
    }

    for (int mi = 0; mi < 4; ++mi)
        for (int ni = 0; ni < 4; ++ni) {
            int n = n0 + wc * 64 + ni * 16 + lr;
            float bv = bias[n];
            for (int j = 0; j < 4; ++j) {
                int m = m0 + wr * 64 + mi * 16 + lg * 4 + j;
                float v = acc[mi][ni][j] + bv;
                int b = m >> 11, t = m & 2047, h = n >> 6, dh = n & 63;
                size_t idx;
                if (which != 2) idx = (((size_t)(b * 16 + h)) * 2048 + t) * 64 + dh;
                else            idx = (((size_t)(b * 16 + h)) * 64 + dh) * 2048 + t;
                Cout[idx] = __float2bfloat16(v);
            }
        }
}

// ---------------- final projection GEMM (64x128 + T2, round-12) -----------
__global__ __launch_bounds__(256)
void gemm_out(const __hip_bfloat16* __restrict__ A,
              const __hip_bfloat16* __restrict__ Bw,
              const float* __restrict__ bias,
              float* __restrict__ Cout)
{
    __shared__ __hip_bfloat16 As[64][64];
    __shared__ __hip_bfloat16 Bs[128][64];
    const int tid = threadIdx.x;
    const int lane = tid & 63, w = tid >> 6;
    const int lr = lane & 15, lg = lane >> 4;
    const int m0 = blockIdx.y * 64, n0 = blockIdx.x * 128;

    f32x4 acc[4][2] = {};
    const int lrow = lane >> 3;
    const int scol = ((lane & 7) ^ lrow) * 8;
    const int rswz = (lr & 7) * 8;

    for (int k0 = 0; k0 < D_; k0 += 64) {
#pragma unroll
        for (int c = 0; c < 2; ++c) {
            __builtin_amdgcn_global_load_lds(
                (const __attribute__((address_space(1))) void*)
                    &A[(size_t)(m0 + w * 16 + c * 8 + lrow) * D_ + k0 + scol],
                (__attribute__((address_space(3))) void*)&As[w * 16 + c * 8][0],
                16, 0, 0);
        }
#pragma unroll
        for (int c = 0; c < 4; ++c) {
            __builtin_amdgcn_global_load_lds(
                (const __attribute__((address_space(1))) void*)
                    &Bw[(size_t)(n0 + w * 32 + c * 8 + lrow) * D_ + k0 + scol],
                (__attribute__((address_space(3))) void*)&Bs[w * 32 + c * 8][0],
                16, 0, 0);
        }
        __syncthreads();
#pragma unroll
        for (int ks = 0; ks < 2; ++ks) {
            bf16x8 af[4], bfr[2];
            for (int mi = 0; mi < 4; ++mi)
                af[mi]  = *(const bf16x8*)&As[mi * 16 + lr][(ks * 32 + lg * 8) ^ rswz];
            for (int ni = 0; ni < 2; ++ni)
                bfr[ni] = *(const bf16x8*)&Bs[w * 32 + ni * 16 + lr][(ks * 32 + lg * 8) ^ rswz];
            for (int mi = 0; mi < 4; ++mi)
                for (int ni = 0; ni < 2; ++ni)
                    acc[mi][ni] = MFMA16(af[mi], bfr[ni], acc[mi][ni]);
        }
        __syncthreads();
    }

    for (int mi = 0; mi < 4; ++mi)
        for (int ni = 0; ni < 2; ++ni) {
            int n = n0 + w * 32 + ni * 16 + lr;
            float bv = bias[n];
            for (int j = 0; j < 4; ++j) {
                int m = m0 + mi * 16 + lg * 4 + j;
                Cout[(size_t)m * D_ + n] = acc[mi][ni][j] + bv;
            }
        }
}

// ---------------- causal flash attention (round-12 passing version) -------
// grid (bh=32, 32): 2-wave blocks, 64 q-rows (wave wv owns q0=qc*64+wv*32);
// qc = 31-by (heavy first). K/V staged via coalesced global_load_lds with
// XOR swizzle. Double buffered, 1 barrier/tile. Raw v_exp_f32, balanced
// trees, setprio(1) around MFMA clusters. Cross-half reduce: __shfl_xor.
__global__ __launch_bounds__(128, 2)
void attn_kern(const __hip_bfloat16* __restrict__ Qh,
               const __hip_bfloat16* __restrict__ Kh,
               const __hip_bfloat16* __restrict__ Vt,
               __hip_bfloat16* __restrict__ Oa)
{
    __shared__ __hip_bfloat16 Ks[2][64][64];
    __shared__ __hip_bfloat16 Vs[2][64][64];

    const int tid = threadIdx.x;
    const int lane = tid & 63, wv = tid >> 6;
    const int ql = lane & 31, hi = lane >> 5;
    const int bh = blockIdx.x;
    const int qc = 31 - blockIdx.y;       // heavy chunks dispatch first
    const int q0 = qc * 64 + wv * 32;

    const __hip_bfloat16* Qb = Qh + (size_t)bh * T_ * DH_;
    const __hip_bfloat16* Kb = Kh + (size_t)bh * T_ * DH_;
    const __hip_bfloat16* Vb = Vt + (size_t)bh * DH_ * T_;

    const int strow = tid >> 3;                               // 0..15
    const int stcol = ((tid & 7) * 8) ^ (((tid >> 3) & 7) * 8); // elems

    bf16x8 qf[4];
#pragma unroll
    for (int dd = 0; dd < 4; ++dd)
        qf[dd] = *(const bf16x8*)&Qb[(size_t)(q0 + ql) * DH_ + dd * 16 + hi * 8];

    f32x16 accO0 = {}, accO1 = {};
    float m_r = -1e30f, l_r = 0.f;
    const float C2 = 0.18033688011112042f;  // (1/sqrt(64)) * log2(e)
    const int kswz = (ql & 7) * 8;          // read-side XOR (elems)

    const int nkv = qc + 1;

#define STAGE(BUF, KV)                                                        \
    {                                                                         \
        char* kd = (char*)&Ks[BUF][0][0] + wv * 1024;                         \
        char* vd = (char*)&Vs[BUF][0][0] + wv * 1024;                         \
        _Pragma("unroll")                                                     \
        for (int s = 0; s < 4; ++s) {                                         \
            __builtin_amdgcn_global_load_lds(                                 \
                (const __attribute__((address_space(1))) void*)               \
                    &Kb[(size_t)((KV) + s * 16 + strow) * DH_ + stcol],       \
                (__attribute__((address_space(3))) void*)(kd + s * 2048),     \
                16, 0, 0);                                                    \
            __builtin_amdgcn_global_load_lds(                                 \
                (const __attribute__((address_space(1))) void*)               \
                    &Vb[(size_t)(s * 16 + strow) * T_ + (KV) + stcol],        \
                (__attribute__((address_space(3))) void*)(vd + s * 2048),     \
                16, 0, 0);                                                    \
        }                                                                     \
    }

    STAGE(0, 0)
    __syncthreads();

    int buf = 0;
    for (int it = 0; it < nkv; ++it) {
        const int kv0 = it * 64;
        if (it + 1 < nkv) STAGE(buf ^ 1, kv0 + 64)

        const bool act1 = (kv0 + 32 <= q0);

        bf16x8 kf0[4], kf1[4];
#pragma unroll
        for (int dd = 0; dd < 4; ++dd)
            kf0[dd] = *(const bf16x8*)&Ks[buf][ql][(dd * 16 + hi * 8) ^ kswz];
        if (act1) {
#pragma unroll
            for (int dd = 0; dd < 4; ++dd)
                kf1[dd] = *(const bf16x8*)&Ks[buf][32 + ql][(dd * 16 + hi * 8) ^ kswz];
        }

        f32x16 s0 = {}, s1 = {};
        __builtin_amdgcn_s_setprio(1);
#pragma unroll
        for (int dd = 0; dd < 4; ++dd) s0 = MFMA32(kf0[dd], qf[dd], s0);
        if (act1) {
#pragma unroll
            for (int dd = 0; dd < 4; ++dd) s1 = MFMA32(kf1[dd], qf[dd], s1);
        }
        __builtin_amdgcn_s_setprio(0);

        if (kv0 == q0) {
#pragma unroll
            for (int r = 0; r < 16; ++r)
                if ((r & 3) + 8 * (r >> 2) + 4 * hi > ql) s0[r] = -1e30f;
        }
        if (act1 && kv0 + 32 == q0) {
#pragma unroll
            for (int r = 0; r < 16; ++r)
                if ((r & 3) + 8 * (r >> 2) + 4 * hi > ql) s1[r] = -1e30f;
        }

        float mx[16];
#pragma unroll
        for (int r = 0; r < 16; ++r)
            mx[r] = act1 ? fmaxf(s0[r], s1[r]) : s0[r];
#pragma unroll
        for (int off = 8; off > 0; off >>= 1)
#pragma unroll
            for (int r = 0; r < off; ++r) mx[r] = fmaxf(mx[r], mx[r + off]);
        float rmax = fmaxf(mx[0], __shfl_xor(mx[0], 32));

        float mnew = fmaxf(m_r, rmax);
        const bool defer = __all((rmax - m_r) * C2 <= 8.0f);  // T13
        if (defer) mnew = m_r;
        const float mc = mnew * C2;

        float p0[16], p1[16];
#pragma unroll
        for (int r = 0; r < 16; ++r)
            p0[r] = EXP2(__builtin_fmaf(s0[r], C2, -mc));
        if (act1) {
#pragma unroll
            for (int r = 0; r < 16; ++r)
                p1[r] = EXP2(__builtin_fmaf(s1[r], C2, -mc));
        }
        float sm[16];
#pragma unroll
        for (int r = 0; r < 16; ++r)
            sm[r] = act1 ? (p0[r] + p1[r]) : p0[r];
#pragma unroll
        for (int off = 8; off > 0; off >>= 1)
#pragma unroll
            for (int r = 0; r < off; ++r) sm[r] += sm[r + off];
        float rsum = sm[0] + __shfl_xor(sm[0], 32);

        unsigned int pk0[8], pk1[8];
#pragma unroll
        for (int j = 0; j < 8; ++j)
            asm("v_cvt_pk_bf16_f32 %0, %1, %2"
                : "=v"(pk0[j]) : "v"(p0[2 * j]), "v"(p0[2 * j + 1]));
        if (act1) {
#pragma unroll
            for (int j = 0; j < 8; ++j)
                asm("v_cvt_pk_bf16_f32 %0, %1, %2"
                    : "=v"(pk1[j]) : "v"(p1[2 * j]), "v"(p1[2 * j + 1]));
        }

        float alpha = 1.f;
        if (!defer) {
            alpha = EXP2(__builtin_fmaf(m_r, C2, -mc));
#pragma unroll
            for (int r = 0; r < 16; ++r) {
                float al = __shfl(alpha, (r & 3) + 8 * (r >> 2) + 4 * hi);
                accO0[r] *= al;
                accO1[r] *= al;
            }
        }
        l_r = l_r * alpha + rsum;
        m_r = mnew;

        bf16x8 vf0[4], vf1[4];
#pragma unroll
        for (int ks = 0; ks < 4; ++ks) {
            vf0[ks] = *(const bf16x8*)&Vs[buf][ql][(ks * 16 + hi * 8) ^ kswz];
            vf1[ks] = *(const bf16x8*)&Vs[buf][32 + ql][(ks * 16 + hi * 8) ^ kswz];
        }

        // permlane32_swap (vdst[32:63] <-> vsrc[0:31]); distinct-valued
        // operands only (verified round-6 PV pattern).
        union U { unsigned int u[4]; bf16x8 v; };
        asm volatile("v_permlane32_swap_b32 %0, %1" : "+v"(pk0[0]), "+v"(pk0[2]));
        asm volatile("v_permlane32_swap_b32 %0, %1" : "+v"(pk0[1]), "+v"(pk0[3]));
        asm volatile("v_permlane32_swap_b32 %0, %1" : "+v"(pk0[4]), "+v"(pk0[6]));
        asm volatile("v_permlane32_swap_b32 %0, %1" : "+v"(pk0[5]), "+v"(pk0[7]));
        U t0, t1;
        t0.u[0] = pk0[0]; t0.u[1] = pk0[1]; t0.u[2] = pk0[2]; t0.u[3] = pk0[3];
        t1.u[0] = pk0[4]; t1.u[1] = pk0[5]; t1.u[2] = pk0[6]; t1.u[3] = pk0[7];
        __builtin_amdgcn_s_setprio(1);
        accO0 = MFMA32(t0.v, vf0[0], accO0);
        accO1 = MFMA32(t0.v, vf1[0], accO1);
        accO0 = MFMA32(t1.v, vf0[1], accO0);
        accO1 = MFMA32(t1.v, vf1[1], accO1);
        __builtin_amdgcn_s_setprio(0);
        if (act1) {
            asm volatile("v_permlane32_swap_b32 %0, %1" : "+v"(pk1[0]), "+v"(pk1[2]));
            asm volatile("v_permlane32_swap_b32 %0, %1" : "+v"(pk1[1]), "+v"(pk1[3]));
            asm volatile("v_permlane32_swap_b32 %0, %1" : "+v"(pk1[4]), "+v"(pk1[6]));
            asm volatile("v_permlane32_swap_b32 %0, %1" : "+v"(pk1[5]), "+v"(pk1[7]));
            U t2, t3;
            t2.u[0] = pk1[0]; t2.u[1] = pk1[1]; t2.u[2] = pk1[2]; t2.u[3] = pk1[3];
            t3.u[0] = pk1[4]; t3.u[1] = pk1[5]; t3.u[2] = pk1[6]; t3.u[3] = pk1[7];
            __builtin_amdgcn_s_setprio(1);
            accO0 = MFMA32(t2.v, vf0[2], accO0);
            accO1 = MFMA32(t2.v, vf1[2], accO1);
            accO0 = MFMA32(t3.v, vf0[3], accO0);
            accO1 = MFMA32(t3.v, vf1[3], accO1);
            __builtin_amdgcn_s_setprio(0);
        }

        __syncthreads();   // drains stage loads + protects buf reuse
        buf ^= 1;
    }
#undef STAGE

    float invl = 1.f / l_r;
    const int b = bh >> 4, h = bh & 15;
#pragma unroll
    for (int r = 0; r < 16; ++r) {
        const int qr = (r & 3) + 8 * (r >> 2) + 4 * hi;
        float iv = __shfl(invl, qr);
        size_t base = ((size_t)(b * 2048 + q0 + qr)) * 1024 + h * 64;
        Oa[base + ql]      = __float2bfloat16(accO0[r] * iv);
        Oa[base + 32 + ql] = __float2bfloat16(accO1[r] * iv);
    }
}

// --------------------------------------------------------------------------
extern "C" void kernel_launch(void* const* d_in, const int* in_sizes, int n_in,
                              void* d_out, int out_size, void* d_ws, size_t ws_size,
                              hipStream_t stream) {
    const float* x  = (const float*)d_in[0];
    const float* Wq = (const float*)d_in[2];
    const float* bq = (const float*)d_in[3];
    const float* Wk = (const float*)d_in[4];
    const float* bk = (const float*)d_in[5];
    const float* Wv = (const float*)d_in[6];
    const float* bv = (const float*)d_in[7];
    const float* Wo = (const float*)d_in[8];
    const float* bo = (const float*)d_in[9];

    char* ws = (char*)d_ws;
    __hip_bfloat16* xb  = (__hip_bfloat16*)ws;  ws += (size_t)M_ * D_ * 2;
    __hip_bfloat16* wqb = (__hip_bfloat16*)ws;  ws += (size_t)D_ * D_ * 2;
    __hip_bfloat16* wkb = (__hip_bfloat16*)ws;  ws += (size_t)D_ * D_ * 2;
    __hip_bfloat16* wvb = (__hip_bfloat16*)ws;  ws += (size_t)D_ * D_ * 2;
    __hip_bfloat16* wob = (__hip_bfloat16*)ws;  ws += (size_t)D_ * D_ * 2;
    __hip_bfloat16* Qh  = (__hip_bfloat16*)ws;  ws += (size_t)M_ * D_ * 2;
    __hip_bfloat16* Kh  = (__hip_bfloat16*)ws;  ws += (size_t)M_ * D_ * 2;
    __hip_bfloat16* Vth = (__hip_bfloat16*)ws;  ws += (size_t)M_ * D_ * 2;
    __hip_bfloat16* Ao  = (__hip_bfloat16*)ws;  ws += (size_t)M_ * D_ * 2;

    cvt_f32_bf16<<<(M_ * D_ / 4 + 255) / 256, 256, 0, stream>>>(x, xb, M_ * D_ / 4);
    cvt4_f32_bf16<<<dim3((D_ * D_ / 4 + 255) / 256, 4), 256, 0, stream>>>(
        Wq, Wk, Wv, Wo, wqb, wkb, wvb, wob, D_ * D_ / 4);

    gemm_qkv<<<dim3(24, M_ / 128), 256, 0, stream>>>(
        xb, wqb, wkb, wvb, bq, bk, bv, Qh, Kh, Vth);

    attn_kern<<<dim3(BH_, 32), 128, 0, stream>>>(Qh, Kh, Vth, Ao);

    gemm_out<<<dim3(D_ / 128, M_ / 64), 256, 0, stream>>>(Ao, wob, bo, (float*)d_out);
}

// Round 16
// 128.649 us; speedup vs baseline: 1.0898x; 1.0898x over previous
//
#include <hip/hip_runtime.h>
#include <hip/hip_bf16.h>

typedef __attribute__((ext_vector_type(8))) short bf16x8;
typedef __attribute__((ext_vector_type(4))) float f32x4;
typedef __attribute__((ext_vector_type(16))) float f32x16;

#define MFMA16(a,b,c) __builtin_amdgcn_mfma_f32_16x16x32_bf16(a,b,c,0,0,0)
#define MFMA32(a,b,c) __builtin_amdgcn_mfma_f32_32x32x16_bf16(a,b,c,0,0,0)

#if __has_builtin(__builtin_amdgcn_exp2f)
#define EXP2(x) __builtin_amdgcn_exp2f(x)
#else
#define EXP2(x) exp2f(x)
#endif

#define B_   2
#define T_   2048
#define D_   1024
#define H_   16
#define DH_  64
#define BH_  (B_*H_)
#define M_   (B_*T_)   // 4096 token rows

// NOTE (rounds 13/14 lesson): xswap32 built from v_permlane32_swap with both
// operands the same value NaN'd twice (likely coalesced to same-register
// swap; unverified behavior). permlane32_swap is used ONLY with
// distinct-valued operands (verified round-6 PV pattern).
// NOTE (round 15): gemm_qkv at 128x128 tile = 68-71us, SLOWER than 64x128+T2
// (<55us) — small-K occupancy/tail beats arithmetic intensity here.

// ---------------- fp32 -> bf16 converts -----------------------------------
__global__ void cvt_f32_bf16(const float* __restrict__ in,
                             __hip_bfloat16* __restrict__ out, int n4) {
    int i = blockIdx.x * blockDim.x + threadIdx.x;
    if (i >= n4) return;
    float4 v = ((const float4*)in)[i];
    union { ushort4 u; __hip_bfloat16 h[4]; } r;
    r.h[0] = __float2bfloat16(v.x);
    r.h[1] = __float2bfloat16(v.y);
    r.h[2] = __float2bfloat16(v.z);
    r.h[3] = __float2bfloat16(v.w);
    ((ushort4*)out)[i] = r.u;
}

__global__ void cvt4_f32_bf16(const float* __restrict__ w0, const float* __restrict__ w1,
                              const float* __restrict__ w2, const float* __restrict__ w3,
                              __hip_bfloat16* __restrict__ o0, __hip_bfloat16* __restrict__ o1,
                              __hip_bfloat16* __restrict__ o2, __hip_bfloat16* __restrict__ o3,
                              int n4) {
    int i = blockIdx.x * blockDim.x + threadIdx.x;
    if (i >= n4) return;
    const float* in = (blockIdx.y == 0) ? w0 : (blockIdx.y == 1) ? w1 : (blockIdx.y == 2) ? w2 : w3;
    __hip_bfloat16* out = (blockIdx.y == 0) ? o0 : (blockIdx.y == 1) ? o1 : (blockIdx.y == 2) ? o2 : o3;
    float4 v = ((const float4*)in)[i];
    union { ushort4 u; __hip_bfloat16 h[4]; } r;
    r.h[0] = __float2bfloat16(v.x);
    r.h[1] = __float2bfloat16(v.y);
    r.h[2] = __float2bfloat16(v.z);
    r.h[3] = __float2bfloat16(v.w);
    ((ushort4*)out)[i] = r.u;
}

// ---------------- fused QKV GEMM (BM=64/BN=128 + T2 XOR-swizzle) ----------
// Round-12 version (best measured). 1536 blocks (6/CU). Pre-swizzled global
// src for global_load_lds (linear LDS dest) + same-XOR read (rule 21).
__global__ __launch_bounds__(256)
void gemm_qkv(const __hip_bfloat16* __restrict__ A,
              const __hip_bfloat16* __restrict__ Wq_, const __hip_bfloat16* __restrict__ Wk_,
              const __hip_bfloat16* __restrict__ Wv_,
              const float* __restrict__ bq_, const float* __restrict__ bk_,
              const float* __restrict__ bv_,
              __hip_bfloat16* __restrict__ Qh, __hip_bfloat16* __restrict__ Kh,
              __hip_bfloat16* __restrict__ Vth)
{
    __shared__ __hip_bfloat16 As[64][64];
    __shared__ __hip_bfloat16 Bs[128][64];
    const int tid = threadIdx.x;
    const int lane = tid & 63, w = tid >> 6;
    const int lr = lane & 15, lg = lane >> 4;
    const int which = blockIdx.x >> 3;
    const int n0 = (blockIdx.x & 7) * 128;
    const int m0 = blockIdx.y * 64;

    const __hip_bfloat16* Bw = (which == 0) ? Wq_ : (which == 1) ? Wk_ : Wv_;
    const float* bias         = (which == 0) ? bq_ : (which == 1) ? bk_ : bv_;
    __hip_bfloat16* Cout      = (which == 0) ? Qh  : (which == 1) ? Kh  : Vth;

    f32x4 acc[4][2] = {};

    const int lrow = lane >> 3;                       // 0..7 (row within 8-group)
    const int scol = ((lane & 7) ^ lrow) * 8;         // pre-swizzled source col
    const int rswz = (lr & 7) * 8;                    // read-side XOR (elems)

    for (int k0 = 0; k0 < D_; k0 += 64) {
#pragma unroll
        for (int c = 0; c < 2; ++c) {
            __builtin_amdgcn_global_load_lds(
                (const __attribute__((address_space(1))) void*)
                    &A[(size_t)(m0 + w * 16 + c * 8 + lrow) * D_ + k0 + scol],
                (__attribute__((address_space(3))) void*)&As[w * 16 + c * 8][0],
                16, 0, 0);
        }
#pragma unroll
        for (int c = 0; c < 4; ++c) {
            __builtin_amdgcn_global_load_lds(
                (const __attribute__((address_space(1))) void*)
                    &Bw[(size_t)(n0 + w * 32 + c * 8 + lrow) * D_ + k0 + scol],
                (__attribute__((address_space(3))) void*)&Bs[w * 32 + c * 8][0],
                16, 0, 0);
        }
        __syncthreads();
#pragma unroll
        for (int ks = 0; ks < 2; ++ks) {
            bf16x8 af[4], bfr[2];
            for (int mi = 0; mi < 4; ++mi)
                af[mi]  = *(const bf16x8*)&As[mi * 16 + lr][(ks * 32 + lg * 8) ^ rswz];
            for (int ni = 0; ni < 2; ++ni)
                bfr[ni] = *(const bf16x8*)&Bs[w * 32 + ni * 16 + lr][(ks * 32 + lg * 8) ^ rswz];
            for (int mi = 0; mi < 4; ++mi)
                for (int ni = 0; ni < 2; ++ni)
                    acc[mi][ni] = MFMA16(af[mi], bfr[ni], acc[mi][ni]);
        }
        __syncthreads();
    }

    for (int mi = 0; mi < 4; ++mi)
        for (int ni = 0; ni < 2; ++ni) {
            int n = n0 + w * 32 + ni * 16 + lr;
            float bv = bias[n];
            for (int j = 0; j < 4; ++j) {
                int m = m0 + mi * 16 + lg * 4 + j;
                float v = acc[mi][ni][j] + bv;
                int b = m >> 11, t = m & 2047, h = n >> 6, dh = n & 63;
                size_t idx;
                if (which != 2) idx = (((size_t)(b * 16 + h)) * 2048 + t) * 64 + dh;
                else            idx = (((size_t)(b * 16 + h)) * 64 + dh) * 2048 + t;
                Cout[idx] = __float2bfloat16(v);
            }
        }
}

// ---------------- final projection GEMM (64x128 + T2, round-12) -----------
__global__ __launch_bounds__(256)
void gemm_out(const __hip_bfloat16* __restrict__ A,
              const __hip_bfloat16* __restrict__ Bw,
              const float* __restrict__ bias,
              float* __restrict__ Cout)
{
    __shared__ __hip_bfloat16 As[64][64];
    __shared__ __hip_bfloat16 Bs[128][64];
    const int tid = threadIdx.x;
    const int lane = tid & 63, w = tid >> 6;
    const int lr = lane & 15, lg = lane >> 4;
    const int m0 = blockIdx.y * 64, n0 = blockIdx.x * 128;

    f32x4 acc[4][2] = {};
    const int lrow = lane >> 3;
    const int scol = ((lane & 7) ^ lrow) * 8;
    const int rswz = (lr & 7) * 8;

    for (int k0 = 0; k0 < D_; k0 += 64) {
#pragma unroll
        for (int c = 0; c < 2; ++c) {
            __builtin_amdgcn_global_load_lds(
                (const __attribute__((address_space(1))) void*)
                    &A[(size_t)(m0 + w * 16 + c * 8 + lrow) * D_ + k0 + scol],
                (__attribute__((address_space(3))) void*)&As[w * 16 + c * 8][0],
                16, 0, 0);
        }
#pragma unroll
        for (int c = 0; c < 4; ++c) {
            __builtin_amdgcn_global_load_lds(
                (const __attribute__((address_space(1))) void*)
                    &Bw[(size_t)(n0 + w * 32 + c * 8 + lrow) * D_ + k0 + scol],
                (__attribute__((address_space(3))) void*)&Bs[w * 32 + c * 8][0],
                16, 0, 0);
        }
        __syncthreads();
#pragma unroll
        for (int ks = 0; ks < 2; ++ks) {
            bf16x8 af[4], bfr[2];
            for (int mi = 0; mi < 4; ++mi)
                af[mi]  = *(const bf16x8*)&As[mi * 16 + lr][(ks * 32 + lg * 8) ^ rswz];
            for (int ni = 0; ni < 2; ++ni)
                bfr[ni] = *(const bf16x8*)&Bs[w * 32 + ni * 16 + lr][(ks * 32 + lg * 8) ^ rswz];
            for (int mi = 0; mi < 4; ++mi)
                for (int ni = 0; ni < 2; ++ni)
                    acc[mi][ni] = MFMA16(af[mi], bfr[ni], acc[mi][ni]);
        }
        __syncthreads();
    }

    for (int mi = 0; mi < 4; ++mi)
        for (int ni = 0; ni < 2; ++ni) {
            int n = n0 + w * 32 + ni * 16 + lr;
            float bv = bias[n];
            for (int j = 0; j < 4; ++j) {
                int m = m0 + mi * 16 + lg * 4 + j;
                Cout[(size_t)m * D_ + n] = acc[mi][ni][j] + bv;
            }
        }
}

// ---------------- causal flash attention (round-12 passing version) -------
// grid (bh=32, 32): 2-wave blocks, 64 q-rows (wave wv owns q0=qc*64+wv*32);
// qc = 31-by (heavy first). K/V staged via coalesced global_load_lds with
// XOR swizzle. Double buffered, 1 barrier/tile. Raw v_exp_f32, balanced
// trees, setprio(1) around MFMA clusters. Cross-half reduce: __shfl_xor.
__global__ __launch_bounds__(128, 2)
void attn_kern(const __hip_bfloat16* __restrict__ Qh,
               const __hip_bfloat16* __restrict__ Kh,
               const __hip_bfloat16* __restrict__ Vt,
               __hip_bfloat16* __restrict__ Oa)
{
    __shared__ __hip_bfloat16 Ks[2][64][64];
    __shared__ __hip_bfloat16 Vs[2][64][64];

    const int tid = threadIdx.x;
    const int lane = tid & 63, wv = tid >> 6;
    const int ql = lane & 31, hi = lane >> 5;
    const int bh = blockIdx.x;
    const int qc = 31 - blockIdx.y;       // heavy chunks dispatch first
    const int q0 = qc * 64 + wv * 32;

    const __hip_bfloat16* Qb = Qh + (size_t)bh * T_ * DH_;
    const __hip_bfloat16* Kb = Kh + (size_t)bh * T_ * DH_;
    const __hip_bfloat16* Vb = Vt + (size_t)bh * DH_ * T_;

    const int strow = tid >> 3;                               // 0..15
    const int stcol = ((tid & 7) * 8) ^ (((tid >> 3) & 7) * 8); // elems

    bf16x8 qf[4];
#pragma unroll
    for (int dd = 0; dd < 4; ++dd)
        qf[dd] = *(const bf16x8*)&Qb[(size_t)(q0 + ql) * DH_ + dd * 16 + hi * 8];

    f32x16 accO0 = {}, accO1 = {};
    float m_r = -1e30f, l_r = 0.f;
    const float C2 = 0.18033688011112042f;  // (1/sqrt(64)) * log2(e)
    const int kswz = (ql & 7) * 8;          // read-side XOR (elems)

    const int nkv = qc + 1;

#define STAGE(BUF, KV)                                                        \
    {                                                                         \
        char* kd = (char*)&Ks[BUF][0][0] + wv * 1024;                         \
        char* vd = (char*)&Vs[BUF][0][0] + wv * 1024;                         \
        _Pragma("unroll")                                                     \
        for (int s = 0; s < 4; ++s) {                                         \
            __builtin_amdgcn_global_load_lds(                                 \
                (const __attribute__((address_space(1))) void*)               \
                    &Kb[(size_t)((KV) + s * 16 + strow) * DH_ + stcol],       \
                (__attribute__((address_space(3))) void*)(kd + s * 2048),     \
                16, 0, 0);                                                    \
            __builtin_amdgcn_global_load_lds(                                 \
                (const __attribute__((address_space(1))) void*)               \
                    &Vb[(size_t)(s * 16 + strow) * T_ + (KV) + stcol],        \
                (__attribute__((address_space(3))) void*)(vd + s * 2048),     \
                16, 0, 0);                                                    \
        }                                                                     \
    }

    STAGE(0, 0)
    __syncthreads();

    int buf = 0;
    for (int it = 0; it < nkv; ++it) {
        const int kv0 = it * 64;
        if (it + 1 < nkv) STAGE(buf ^ 1, kv0 + 64)

        const bool act1 = (kv0 + 32 <= q0);

        bf16x8 kf0[4], kf1[4];
#pragma unroll
        for (int dd = 0; dd < 4; ++dd)
            kf0[dd] = *(const bf16x8*)&Ks[buf][ql][(dd * 16 + hi * 8) ^ kswz];
        if (act1) {
#pragma unroll
            for (int dd = 0; dd < 4; ++dd)
                kf1[dd] = *(const bf16x8*)&Ks[buf][32 + ql][(dd * 16 + hi * 8) ^ kswz];
        }

        f32x16 s0 = {}, s1 = {};
        __builtin_amdgcn_s_setprio(1);
#pragma unroll
        for (int dd = 0; dd < 4; ++dd) s0 = MFMA32(kf0[dd], qf[dd], s0);
        if (act1) {
#pragma unroll
            for (int dd = 0; dd < 4; ++dd) s1 = MFMA32(kf1[dd], qf[dd], s1);
        }
        __builtin_amdgcn_s_setprio(0);

        if (kv0 == q0) {
#pragma unroll
            for (int r = 0; r < 16; ++r)
                if ((r & 3) + 8 * (r >> 2) + 4 * hi > ql) s0[r] = -1e30f;
        }
        if (act1 && kv0 + 32 == q0) {
#pragma unroll
            for (int r = 0; r < 16; ++r)
                if ((r & 3) + 8 * (r >> 2) + 4 * hi > ql) s1[r] = -1e30f;
        }

        float mx[16];
#pragma unroll
        for (int r = 0; r < 16; ++r)
            mx[r] = act1 ? fmaxf(s0[r], s1[r]) : s0[r];
#pragma unroll
        for (int off = 8; off > 0; off >>= 1)
#pragma unroll
            for (int r = 0; r < off; ++r) mx[r] = fmaxf(mx[r], mx[r + off]);
        float rmax = fmaxf(mx[0], __shfl_xor(mx[0], 32));

        float mnew = fmaxf(m_r, rmax);
        const bool defer = __all((rmax - m_r) * C2 <= 8.0f);  // T13
        if (defer) mnew = m_r;
        const float mc = mnew * C2;

        float p0[16], p1[16];
#pragma unroll
        for (int r = 0; r < 16; ++r)
            p0[r] = EXP2(__builtin_fmaf(s0[r], C2, -mc));
        if (act1) {
#pragma unroll
            for (int r = 0; r < 16; ++r)
                p1[r] = EXP2(__builtin_fmaf(s1[r], C2, -mc));
        }
        float sm[16];
#pragma unroll
        for (int r = 0; r < 16; ++r)
            sm[r] = act1 ? (p0[r] + p1[r]) : p0[r];
#pragma unroll
        for (int off = 8; off > 0; off >>= 1)
#pragma unroll
            for (int r = 0; r < off; ++r) sm[r] += sm[r + off];
        float rsum = sm[0] + __shfl_xor(sm[0], 32);

        unsigned int pk0[8], pk1[8];
#pragma unroll
        for (int j = 0; j < 8; ++j)
            asm("v_cvt_pk_bf16_f32 %0, %1, %2"
                : "=v"(pk0[j]) : "v"(p0[2 * j]), "v"(p0[2 * j + 1]));
        if (act1) {
#pragma unroll
            for (int j = 0; j < 8; ++j)
                asm("v_cvt_pk_bf16_f32 %0, %1, %2"
                    : "=v"(pk1[j]) : "v"(p1[2 * j]), "v"(p1[2 * j + 1]));
        }

        float alpha = 1.f;
        if (!defer) {
            alpha = EXP2(__builtin_fmaf(m_r, C2, -mc));
#pragma unroll
            for (int r = 0; r < 16; ++r) {
                float al = __shfl(alpha, (r & 3) + 8 * (r >> 2) + 4 * hi);
                accO0[r] *= al;
                accO1[r] *= al;
            }
        }
        l_r = l_r * alpha + rsum;
        m_r = mnew;

        bf16x8 vf0[4], vf1[4];
#pragma unroll
        for (int ks = 0; ks < 4; ++ks) {
            vf0[ks] = *(const bf16x8*)&Vs[buf][ql][(ks * 16 + hi * 8) ^ kswz];
            vf1[ks] = *(const bf16x8*)&Vs[buf][32 + ql][(ks * 16 + hi * 8) ^ kswz];
        }

        // permlane32_swap (vdst[32:63] <-> vsrc[0:31]); distinct-valued
        // operands only (verified round-6 PV pattern).
        union U { unsigned int u[4]; bf16x8 v; };
        asm volatile("v_permlane32_swap_b32 %0, %1" : "+v"(pk0[0]), "+v"(pk0[2]));
        asm volatile("v_permlane32_swap_b32 %0, %1" : "+v"(pk0[1]), "+v"(pk0[3]));
        asm volatile("v_permlane32_swap_b32 %0, %1" : "+v"(pk0[4]), "+v"(pk0[6]));
        asm volatile("v_permlane32_swap_b32 %0, %1" : "+v"(pk0[5]), "+v"(pk0[7]));
        U t0, t1;
        t0.u[0] = pk0[0]; t0.u[1] = pk0[1]; t0.u[2] = pk0[2]; t0.u[3] = pk0[3];
        t1.u[0] = pk0[4]; t1.u[1] = pk0[5]; t1.u[2] = pk0[6]; t1.u[3] = pk0[7];
        __builtin_amdgcn_s_setprio(1);
        accO0 = MFMA32(t0.v, vf0[0], accO0);
        accO1 = MFMA32(t0.v, vf1[0], accO1);
        accO0 = MFMA32(t1.v, vf0[1], accO0);
        accO1 = MFMA32(t1.v, vf1[1], accO1);
        __builtin_amdgcn_s_setprio(0);
        if (act1) {
            asm volatile("v_permlane32_swap_b32 %0, %1" : "+v"(pk1[0]), "+v"(pk1[2]));
            asm volatile("v_permlane32_swap_b32 %0, %1" : "+v"(pk1[1]), "+v"(pk1[3]));
            asm volatile("v_permlane32_swap_b32 %0, %1" : "+v"(pk1[4]), "+v"(pk1[6]));
            asm volatile("v_permlane32_swap_b32 %0, %1" : "+v"(pk1[5]), "+v"(pk1[7]));
            U t2, t3;
            t2.u[0] = pk1[0]; t2.u[1] = pk1[1]; t2.u[2] = pk1[2]; t2.u[3] = pk1[3];
            t3.u[0] = pk1[4]; t3.u[1] = pk1[5]; t3.u[2] = pk1[6]; t3.u[3] = pk1[7];
            __builtin_amdgcn_s_setprio(1);
            accO0 = MFMA32(t2.v, vf0[2], accO0);
            accO1 = MFMA32(t2.v, vf1[2], accO1);
            accO0 = MFMA32(t3.v, vf0[3], accO0);
            accO1 = MFMA32(t3.v, vf1[3], accO1);
            __builtin_amdgcn_s_setprio(0);
        }

        __syncthreads();   // drains stage loads + protects buf reuse
        buf ^= 1;
    }
#undef STAGE

    float invl = 1.f / l_r;
    const int b = bh >> 4, h = bh & 15;
#pragma unroll
    for (int r = 0; r < 16; ++r) {
        const int qr = (r & 3) + 8 * (r >> 2) + 4 * hi;
        float iv = __shfl(invl, qr);
        size_t base = ((size_t)(b * 2048 + q0 + qr)) * 1024 + h * 64;
        Oa[base + ql]      = __float2bfloat16(accO0[r] * iv);
        Oa[base + 32 + ql] = __float2bfloat16(accO1[r] * iv);
    }
}

// --------------------------------------------------------------------------
extern "C" void kernel_launch(void* const* d_in, const int* in_sizes, int n_in,
                              void* d_out, int out_size, void* d_ws, size_t ws_size,
                              hipStream_t stream) {
    const float* x  = (const float*)d_in[0];
    const float* Wq = (const float*)d_in[2];
    const float* bq = (const float*)d_in[3];
    const float* Wk = (const float*)d_in[4];
    const float* bk = (const float*)d_in[5];
    const float* Wv = (const float*)d_in[6];
    const float* bv = (const float*)d_in[7];
    const float* Wo = (const float*)d_in[8];
    const float* bo = (const float*)d_in[9];

    char* ws = (char*)d_ws;
    __hip_bfloat16* xb  = (__hip_bfloat16*)ws;  ws += (size_t)M_ * D_ * 2;
    __hip_bfloat16* wqb = (__hip_bfloat16*)ws;  ws += (size_t)D_ * D_ * 2;
    __hip_bfloat16* wkb = (__hip_bfloat16*)ws;  ws += (size_t)D_ * D_ * 2;
    __hip_bfloat16* wvb = (__hip_bfloat16*)ws;  ws += (size_t)D_ * D_ * 2;
    __hip_bfloat16* wob = (__hip_bfloat16*)ws;  ws += (size_t)D_ * D_ * 2;
    __hip_bfloat16* Qh  = (__hip_bfloat16*)ws;  ws += (size_t)M_ * D_ * 2;
    __hip_bfloat16* Kh  = (__hip_bfloat16*)ws;  ws += (size_t)M_ * D_ * 2;
    __hip_bfloat16* Vth = (__hip_bfloat16*)ws;  ws += (size_t)M_ * D_ * 2;
    __hip_bfloat16* Ao  = (__hip_bfloat16*)ws;  ws += (size_t)M_ * D_ * 2;

    cvt_f32_bf16<<<(M_ * D_ / 4 + 255) / 256, 256, 0, stream>>>(x, xb, M_ * D_ / 4);
    cvt4_f32_bf16<<<dim3((D_ * D_ / 4 + 255) / 256, 4), 256, 0, stream>>>(
        Wq, Wk, Wv, Wo, wqb, wkb, wvb, wob, D_ * D_ / 4);

    gemm_qkv<<<dim3(24, M_ / 64), 256, 0, stream>>>(
        xb, wqb, wkb, wvb, bq, bk, bv, Qh, Kh, Vth);

    attn_kern<<<dim3(BH_, 32), 128, 0, stream>>>(Qh, Kh, Vth, Ao);

    gemm_out<<<dim3(D_ / 128, M_ / 64), 256, 0, stream>>>(Ao, wob, bo, (float*)d_out);
}

// Round 17
// 127.991 us; speedup vs baseline: 1.0954x; 1.0051x over previous
//
#include <hip/hip_runtime.h>
#include <hip/hip_bf16.h>

typedef __attribute__((ext_vector_type(8))) short bf16x8;
typedef __attribute__((ext_vector_type(4))) float f32x4;
typedef __attribute__((ext_vector_type(16))) float f32x16;

#define MFMA16(a,b,c) __builtin_amdgcn_mfma_f32_16x16x32_bf16(a,b,c,0,0,0)
#define MFMA32(a,b,c) __builtin_amdgcn_mfma_f32_32x32x16_bf16(a,b,c,0,0,0)

#if __has_builtin(__builtin_amdgcn_exp2f)
#define EXP2(x) __builtin_amdgcn_exp2f(x)
#else
#define EXP2(x) exp2f(x)
#endif

#define B_   2
#define T_   2048
#define D_   1024
#define H_   16
#define DH_  64
#define BH_  (B_*H_)
#define M_   (B_*T_)   // 4096 token rows

// NOTE (R13/14): permlane32_swap with same-valued operands = NaN (banned).
// NOTE (R15): gemm_qkv 128x128 tile slower than 64x128 at K=1024 (banned).
// R17: attn gets 3-buffer 2-deep prefetch + counted vmcnt(8) (T4) — the
// __syncthreads vmcnt(0) drain put stage latency on every iteration.

// ---------------- fp32 -> bf16 converts -----------------------------------
__global__ void cvt_f32_bf16(const float* __restrict__ in,
                             __hip_bfloat16* __restrict__ out, int n4) {
    int i = blockIdx.x * blockDim.x + threadIdx.x;
    if (i >= n4) return;
    float4 v = ((const float4*)in)[i];
    union { ushort4 u; __hip_bfloat16 h[4]; } r;
    r.h[0] = __float2bfloat16(v.x);
    r.h[1] = __float2bfloat16(v.y);
    r.h[2] = __float2bfloat16(v.z);
    r.h[3] = __float2bfloat16(v.w);
    ((ushort4*)out)[i] = r.u;
}

__global__ void cvt4_f32_bf16(const float* __restrict__ w0, const float* __restrict__ w1,
                              const float* __restrict__ w2, const float* __restrict__ w3,
                              __hip_bfloat16* __restrict__ o0, __hip_bfloat16* __restrict__ o1,
                              __hip_bfloat16* __restrict__ o2, __hip_bfloat16* __restrict__ o3,
                              int n4) {
    int i = blockIdx.x * blockDim.x + threadIdx.x;
    if (i >= n4) return;
    const float* in = (blockIdx.y == 0) ? w0 : (blockIdx.y == 1) ? w1 : (blockIdx.y == 2) ? w2 : w3;
    __hip_bfloat16* out = (blockIdx.y == 0) ? o0 : (blockIdx.y == 1) ? o1 : (blockIdx.y == 2) ? o2 : o3;
    float4 v = ((const float4*)in)[i];
    union { ushort4 u; __hip_bfloat16 h[4]; } r;
    r.h[0] = __float2bfloat16(v.x);
    r.h[1] = __float2bfloat16(v.y);
    r.h[2] = __float2bfloat16(v.z);
    r.h[3] = __float2bfloat16(v.w);
    ((ushort4*)out)[i] = r.u;
}

// ---------------- fused QKV GEMM (BM=64/BN=128 + T2 XOR-swizzle) ----------
__global__ __launch_bounds__(256)
void gemm_qkv(const __hip_bfloat16* __restrict__ A,
              const __hip_bfloat16* __restrict__ Wq_, const __hip_bfloat16* __restrict__ Wk_,
              const __hip_bfloat16* __restrict__ Wv_,
              const float* __restrict__ bq_, const float* __restrict__ bk_,
              const float* __restrict__ bv_,
              __hip_bfloat16* __restrict__ Qh, __hip_bfloat16* __restrict__ Kh,
              __hip_bfloat16* __restrict__ Vth)
{
    __shared__ __hip_bfloat16 As[64][64];
    __shared__ __hip_bfloat16 Bs[128][64];
    const int tid = threadIdx.x;
    const int lane = tid & 63, w = tid >> 6;
    const int lr = lane & 15, lg = lane >> 4;
    const int which = blockIdx.x >> 3;
    const int n0 = (blockIdx.x & 7) * 128;
    const int m0 = blockIdx.y * 64;

    const __hip_bfloat16* Bw = (which == 0) ? Wq_ : (which == 1) ? Wk_ : Wv_;
    const float* bias         = (which == 0) ? bq_ : (which == 1) ? bk_ : bv_;
    __hip_bfloat16* Cout      = (which == 0) ? Qh  : (which == 1) ? Kh  : Vth;

    f32x4 acc[4][2] = {};

    const int lrow = lane >> 3;
    const int scol = ((lane & 7) ^ lrow) * 8;
    const int rswz = (lr & 7) * 8;

    for (int k0 = 0; k0 < D_; k0 += 64) {
#pragma unroll
        for (int c = 0; c < 2; ++c) {
            __builtin_amdgcn_global_load_lds(
                (const __attribute__((address_space(1))) void*)
                    &A[(size_t)(m0 + w * 16 + c * 8 + lrow) * D_ + k0 + scol],
                (__attribute__((address_space(3))) void*)&As[w * 16 + c * 8][0],
                16, 0, 0);
        }
#pragma unroll
        for (int c = 0; c < 4; ++c) {
            __builtin_amdgcn_global_load_lds(
                (const __attribute__((address_space(1))) void*)
                    &Bw[(size_t)(n0 + w * 32 + c * 8 + lrow) * D_ + k0 + scol],
                (__attribute__((address_space(3))) void*)&Bs[w * 32 + c * 8][0],
                16, 0, 0);
        }
        __syncthreads();
#pragma unroll
        for (int ks = 0; ks < 2; ++ks) {
            bf16x8 af[4], bfr[2];
            for (int mi = 0; mi < 4; ++mi)
                af[mi]  = *(const bf16x8*)&As[mi * 16 + lr][(ks * 32 + lg * 8) ^ rswz];
            for (int ni = 0; ni < 2; ++ni)
                bfr[ni] = *(const bf16x8*)&Bs[w * 32 + ni * 16 + lr][(ks * 32 + lg * 8) ^ rswz];
            for (int mi = 0; mi < 4; ++mi)
                for (int ni = 0; ni < 2; ++ni)
                    acc[mi][ni] = MFMA16(af[mi], bfr[ni], acc[mi][ni]);
        }
        __syncthreads();
    }

    for (int mi = 0; mi < 4; ++mi)
        for (int ni = 0; ni < 2; ++ni) {
            int n = n0 + w * 32 + ni * 16 + lr;
            float bv = bias[n];
            for (int j = 0; j < 4; ++j) {
                int m = m0 + mi * 16 + lg * 4 + j;
                float v = acc[mi][ni][j] + bv;
                int b = m >> 11, t = m & 2047, h = n >> 6, dh = n & 63;
                size_t idx;
                if (which != 2) idx = (((size_t)(b * 16 + h)) * 2048 + t) * 64 + dh;
                else            idx = (((size_t)(b * 16 + h)) * 64 + dh) * 2048 + t;
                Cout[idx] = __float2bfloat16(v);
            }
        }
}

// ---------------- final projection GEMM (64x128 + T2) ---------------------
__global__ __launch_bounds__(256)
void gemm_out(const __hip_bfloat16* __restrict__ A,
              const __hip_bfloat16* __restrict__ Bw,
              const float* __restrict__ bias,
              float* __restrict__ Cout)
{
    __shared__ __hip_bfloat16 As[64][64];
    __shared__ __hip_bfloat16 Bs[128][64];
    const int tid = threadIdx.x;
    const int lane = tid & 63, w = tid >> 6;
    const int lr = lane & 15, lg = lane >> 4;
    const int m0 = blockIdx.y * 64, n0 = blockIdx.x * 128;

    f32x4 acc[4][2] = {};
    const int lrow = lane >> 3;
    const int scol = ((lane & 7) ^ lrow) * 8;
    const int rswz = (lr & 7) * 8;

    for (int k0 = 0; k0 < D_; k0 += 64) {
#pragma unroll
        for (int c = 0; c < 2; ++c) {
            __builtin_amdgcn_global_load_lds(
                (const __attribute__((address_space(1))) void*)
                    &A[(size_t)(m0 + w * 16 + c * 8 + lrow) * D_ + k0 + scol],
                (__attribute__((address_space(3))) void*)&As[w * 16 + c * 8][0],
                16, 0, 0);
        }
#pragma unroll
        for (int c = 0; c < 4; ++c) {
            __builtin_amdgcn_global_load_lds(
                (const __attribute__((address_space(1))) void*)
                    &Bw[(size_t)(n0 + w * 32 + c * 8 + lrow) * D_ + k0 + scol],
                (__attribute__((address_space(3))) void*)&Bs[w * 32 + c * 8][0],
                16, 0, 0);
        }
        __syncthreads();
#pragma unroll
        for (int ks = 0; ks < 2; ++ks) {
            bf16x8 af[4], bfr[2];
            for (int mi = 0; mi < 4; ++mi)
                af[mi]  = *(const bf16x8*)&As[mi * 16 + lr][(ks * 32 + lg * 8) ^ rswz];
            for (int ni = 0; ni < 2; ++ni)
                bfr[ni] = *(const bf16x8*)&Bs[w * 32 + ni * 16 + lr][(ks * 32 + lg * 8) ^ rswz];
            for (int mi = 0; mi < 4; ++mi)
                for (int ni = 0; ni < 2; ++ni)
                    acc[mi][ni] = MFMA16(af[mi], bfr[ni], acc[mi][ni]);
        }
        __syncthreads();
    }

    for (int mi = 0; mi < 4; ++mi)
        for (int ni = 0; ni < 2; ++ni) {
            int n = n0 + w * 32 + ni * 16 + lr;
            float bv = bias[n];
            for (int j = 0; j < 4; ++j) {
                int m = m0 + mi * 16 + lg * 4 + j;
                Cout[(size_t)m * D_ + n] = acc[mi][ni][j] + bv;
            }
        }
}

// ---------------- causal flash attention (3-buf, counted vmcnt) -----------
// grid (bh=32, 32): 2-wave blocks, 64 q-rows. Per 64-key tile: K and V^T
// staged via global_load_lds (pre-swizzled src + XOR read). THREE buffers,
// prefetch 2 ahead; loop top: s_waitcnt vmcnt(8) (never 0 except last iter)
// + raw s_barrier -> stage latency spans 2 compute phases (T3/T4). STAGE is
// issued AFTER the barrier so buffer overwrite can't race prior reads.
// vmcnt ledger: 8 loads/STAGE/wave; vmcnt(8) leaves exactly the newest
// batch outstanding, so tile it (issued >=2 batches ago) is drained.
__global__ __launch_bounds__(128, 2)
void attn_kern(const __hip_bfloat16* __restrict__ Qh,
               const __hip_bfloat16* __restrict__ Kh,
               const __hip_bfloat16* __restrict__ Vt,
               __hip_bfloat16* __restrict__ Oa)
{
    __shared__ __hip_bfloat16 Ks[3][64][64];
    __shared__ __hip_bfloat16 Vs[3][64][64];

    const int tid = threadIdx.x;
    const int lane = tid & 63, wv = tid >> 6;
    const int ql = lane & 31, hi = lane >> 5;
    const int bh = blockIdx.x;
    const int qc = 31 - blockIdx.y;       // heavy chunks dispatch first
    const int q0 = qc * 64 + wv * 32;

    const __hip_bfloat16* Qb = Qh + (size_t)bh * T_ * DH_;
    const __hip_bfloat16* Kb = Kh + (size_t)bh * T_ * DH_;
    const __hip_bfloat16* Vb = Vt + (size_t)bh * DH_ * T_;

    const int strow = tid >> 3;                               // 0..15
    const int stcol = ((tid & 7) * 8) ^ (((tid >> 3) & 7) * 8); // elems

    bf16x8 qf[4];
#pragma unroll
    for (int dd = 0; dd < 4; ++dd)
        qf[dd] = *(const bf16x8*)&Qb[(size_t)(q0 + ql) * DH_ + dd * 16 + hi * 8];

    f32x16 accO0 = {}, accO1 = {};
    float m_r = -1e30f, l_r = 0.f;
    const float C2 = 0.18033688011112042f;  // (1/sqrt(64)) * log2(e)
    const int kswz = (ql & 7) * 8;          // read-side XOR (elems)

    const int nkv = qc + 1;

#define STAGE(BUF, KV)                                                        \
    {                                                                         \
        char* kd = (char*)&Ks[BUF][0][0] + wv * 1024;                         \
        char* vd = (char*)&Vs[BUF][0][0] + wv * 1024;                         \
        _Pragma("unroll")                                                     \
        for (int s = 0; s < 4; ++s) {                                         \
            __builtin_amdgcn_global_load_lds(                                 \
                (const __attribute__((address_space(1))) void*)               \
                    &Kb[(size_t)((KV) + s * 16 + strow) * DH_ + stcol],       \
                (__attribute__((address_space(3))) void*)(kd + s * 2048),     \
                16, 0, 0);                                                    \
            __builtin_amdgcn_global_load_lds(                                 \
                (const __attribute__((address_space(1))) void*)               \
                    &Vb[(size_t)(s * 16 + strow) * T_ + (KV) + stcol],        \
                (__attribute__((address_space(3))) void*)(vd + s * 2048),     \
                16, 0, 0);                                                    \
        }                                                                     \
    }

    // prologue: prefetch tiles 0 and 1
    STAGE(0, 0)
    if (nkv > 1) STAGE(1, 64)

    int buf = 0;
    for (int it = 0; it < nkv; ++it) {
        // tile `it` ready after this wait; barrier also guarantees all waves
        // finished reading the buffer we are about to overwrite below.
        if (it == nkv - 1) { asm volatile("s_waitcnt vmcnt(0)" ::: "memory"); }
        else               { asm volatile("s_waitcnt vmcnt(8)" ::: "memory"); }
        __builtin_amdgcn_s_barrier();
        __builtin_amdgcn_sched_barrier(0);

        if (it + 2 < nkv) {
            const int nb = (buf + 2 >= 3) ? buf - 1 : buf + 2;
            STAGE(nb, (it + 2) * 64)
        }

        const int kv0 = it * 64;
        const bool act1 = (kv0 + 32 <= q0);

        bf16x8 kf0[4], kf1[4];
#pragma unroll
        for (int dd = 0; dd < 4; ++dd)
            kf0[dd] = *(const bf16x8*)&Ks[buf][ql][(dd * 16 + hi * 8) ^ kswz];
        if (act1) {
#pragma unroll
            for (int dd = 0; dd < 4; ++dd)
                kf1[dd] = *(const bf16x8*)&Ks[buf][32 + ql][(dd * 16 + hi * 8) ^ kswz];
        }

        f32x16 s0 = {}, s1 = {};
        __builtin_amdgcn_s_setprio(1);
#pragma unroll
        for (int dd = 0; dd < 4; ++dd) s0 = MFMA32(kf0[dd], qf[dd], s0);
        if (act1) {
#pragma unroll
            for (int dd = 0; dd < 4; ++dd) s1 = MFMA32(kf1[dd], qf[dd], s1);
        }
        __builtin_amdgcn_s_setprio(0);

        if (kv0 == q0) {
#pragma unroll
            for (int r = 0; r < 16; ++r)
                if ((r & 3) + 8 * (r >> 2) + 4 * hi > ql) s0[r] = -1e30f;
        }
        if (act1 && kv0 + 32 == q0) {
#pragma unroll
            for (int r = 0; r < 16; ++r)
                if ((r & 3) + 8 * (r >> 2) + 4 * hi > ql) s1[r] = -1e30f;
        }

        float mx[16];
#pragma unroll
        for (int r = 0; r < 16; ++r)
            mx[r] = act1 ? fmaxf(s0[r], s1[r]) : s0[r];
#pragma unroll
        for (int off = 8; off > 0; off >>= 1)
#pragma unroll
            for (int r = 0; r < off; ++r) mx[r] = fmaxf(mx[r], mx[r + off]);
        float rmax = fmaxf(mx[0], __shfl_xor(mx[0], 32));

        float mnew = fmaxf(m_r, rmax);
        const bool defer = __all((rmax - m_r) * C2 <= 8.0f);  // T13
        if (defer) mnew = m_r;
        const float mc = mnew * C2;

        float p0[16], p1[16];
#pragma unroll
        for (int r = 0; r < 16; ++r)
            p0[r] = EXP2(__builtin_fmaf(s0[r], C2, -mc));
        if (act1) {
#pragma unroll
            for (int r = 0; r < 16; ++r)
                p1[r] = EXP2(__builtin_fmaf(s1[r], C2, -mc));
        }
        float sm[16];
#pragma unroll
        for (int r = 0; r < 16; ++r)
            sm[r] = act1 ? (p0[r] + p1[r]) : p0[r];
#pragma unroll
        for (int off = 8; off > 0; off >>= 1)
#pragma unroll
            for (int r = 0; r < off; ++r) sm[r] += sm[r + off];
        float rsum = sm[0] + __shfl_xor(sm[0], 32);

        unsigned int pk0[8], pk1[8];
#pragma unroll
        for (int j = 0; j < 8; ++j)
            asm("v_cvt_pk_bf16_f32 %0, %1, %2"
                : "=v"(pk0[j]) : "v"(p0[2 * j]), "v"(p0[2 * j + 1]));
        if (act1) {
#pragma unroll
            for (int j = 0; j < 8; ++j)
                asm("v_cvt_pk_bf16_f32 %0, %1, %2"
                    : "=v"(pk1[j]) : "v"(p1[2 * j]), "v"(p1[2 * j + 1]));
        }

        float alpha = 1.f;
        if (!defer) {
            alpha = EXP2(__builtin_fmaf(m_r, C2, -mc));
#pragma unroll
            for (int r = 0; r < 16; ++r) {
                float al = __shfl(alpha, (r & 3) + 8 * (r >> 2) + 4 * hi);
                accO0[r] *= al;
                accO1[r] *= al;
            }
        }
        l_r = l_r * alpha + rsum;
        m_r = mnew;

        bf16x8 vf0[4], vf1[4];
#pragma unroll
        for (int ks = 0; ks < 4; ++ks) {
            vf0[ks] = *(const bf16x8*)&Vs[buf][ql][(ks * 16 + hi * 8) ^ kswz];
            vf1[ks] = *(const bf16x8*)&Vs[buf][32 + ql][(ks * 16 + hi * 8) ^ kswz];
        }

        // permlane32_swap (vdst[32:63] <-> vsrc[0:31]); distinct-valued
        // operands only (verified round-6 PV pattern).
        union U { unsigned int u[4]; bf16x8 v; };
        asm volatile("v_permlane32_swap_b32 %0, %1" : "+v"(pk0[0]), "+v"(pk0[2]));
        asm volatile("v_permlane32_swap_b32 %0, %1" : "+v"(pk0[1]), "+v"(pk0[3]));
        asm volatile("v_permlane32_swap_b32 %0, %1" : "+v"(pk0[4]), "+v"(pk0[6]));
        asm volatile("v_permlane32_swap_b32 %0, %1" : "+v"(pk0[5]), "+v"(pk0[7]));
        U t0, t1;
        t0.u[0] = pk0[0]; t0.u[1] = pk0[1]; t0.u[2] = pk0[2]; t0.u[3] = pk0[3];
        t1.u[0] = pk0[4]; t1.u[1] = pk0[5]; t1.u[2] = pk0[6]; t1.u[3] = pk0[7];
        __builtin_amdgcn_s_setprio(1);
        accO0 = MFMA32(t0.v, vf0[0], accO0);
        accO1 = MFMA32(t0.v, vf1[0], accO1);
        accO0 = MFMA32(t1.v, vf0[1], accO0);
        accO1 = MFMA32(t1.v, vf1[1], accO1);
        __builtin_amdgcn_s_setprio(0);
        if (act1) {
            asm volatile("v_permlane32_swap_b32 %0, %1" : "+v"(pk1[0]), "+v"(pk1[2]));
            asm volatile("v_permlane32_swap_b32 %0, %1" : "+v"(pk1[1]), "+v"(pk1[3]));
            asm volatile("v_permlane32_swap_b32 %0, %1" : "+v"(pk1[4]), "+v"(pk1[6]));
            asm volatile("v_permlane32_swap_b32 %0, %1" : "+v"(pk1[5]), "+v"(pk1[7]));
            U t2, t3;
            t2.u[0] = pk1[0]; t2.u[1] = pk1[1]; t2.u[2] = pk1[2]; t2.u[3] = pk1[3];
            t3.u[0] = pk1[4]; t3.u[1] = pk1[5]; t3.u[2] = pk1[6]; t3.u[3] = pk1[7];
            __builtin_amdgcn_s_setprio(1);
            accO0 = MFMA32(t2.v, vf0[2], accO0);
            accO1 = MFMA32(t2.v, vf1[2], accO1);
            accO0 = MFMA32(t3.v, vf0[3], accO0);
            accO1 = MFMA32(t3.v, vf1[3], accO1);
            __builtin_amdgcn_s_setprio(0);
        }

        buf = (buf + 1 >= 3) ? 0 : buf + 1;
    }
#undef STAGE

    float invl = 1.f / l_r;
    const int b = bh >> 4, h = bh & 15;
#pragma unroll
    for (int r = 0; r < 16; ++r) {
        const int qr = (r & 3) + 8 * (r >> 2) + 4 * hi;
        float iv = __shfl(invl, qr);
        size_t base = ((size_t)(b * 2048 + q0 + qr)) * 1024 + h * 64;
        Oa[base + ql]      = __float2bfloat16(accO0[r] * iv);
        Oa[base + 32 + ql] = __float2bfloat16(accO1[r] * iv);
    }
}

// --------------------------------------------------------------------------
extern "C" void kernel_launch(void* const* d_in, const int* in_sizes, int n_in,
                              void* d_out, int out_size, void* d_ws, size_t ws_size,
                              hipStream_t stream) {
    const float* x  = (const float*)d_in[0];
    const float* Wq = (const float*)d_in[2];
    const float* bq = (const float*)d_in[3];
    const float* Wk = (const float*)d_in[4];
    const float* bk = (const float*)d_in[5];
    const float* Wv = (const float*)d_in[6];
    const float* bv = (const float*)d_in[7];
    const float* Wo = (const float*)d_in[8];
    const float* bo = (const float*)d_in[9];

    char* ws = (char*)d_ws;
    __hip_bfloat16* xb  = (__hip_bfloat16*)ws;  ws += (size_t)M_ * D_ * 2;
    __hip_bfloat16* wqb = (__hip_bfloat16*)ws;  ws += (size_t)D_ * D_ * 2;
    __hip_bfloat16* wkb = (__hip_bfloat16*)ws;  ws += (size_t)D_ * D_ * 2;
    __hip_bfloat16* wvb = (__hip_bfloat16*)ws;  ws += (size_t)D_ * D_ * 2;
    __hip_bfloat16* wob = (__hip_bfloat16*)ws;  ws += (size_t)D_ * D_ * 2;
    __hip_bfloat16* Qh  = (__hip_bfloat16*)ws;  ws += (size_t)M_ * D_ * 2;
    __hip_bfloat16* Kh  = (__hip_bfloat16*)ws;  ws += (size_t)M_ * D_ * 2;
    __hip_bfloat16* Vth = (__hip_bfloat16*)ws;  ws += (size_t)M_ * D_ * 2;
    __hip_bfloat16* Ao  = (__hip_bfloat16*)ws;  ws += (size_t)M_ * D_ * 2;

    cvt_f32_bf16<<<(M_ * D_ / 4 + 255) / 256, 256, 0, stream>>>(x, xb, M_ * D_ / 4);
    cvt4_f32_bf16<<<dim3((D_ * D_ / 4 + 255) / 256, 4), 256, 0, stream>>>(
        Wq, Wk, Wv, Wo, wqb, wkb, wvb, wob, D_ * D_ / 4);

    gemm_qkv<<<dim3(24, M_ / 64), 256, 0, stream>>>(
        xb, wqb, wkb, wvb, bq, bk, bv, Qh, Kh, Vth);

    attn_kern<<<dim3(BH_, 32), 128, 0, stream>>>(Qh, Kh, Vth, Ao);

    gemm_out<<<dim3(D_ / 128, M_ / 64), 256, 0, stream>>>(Ao, wob, bo, (float*)d_out);
}